// Round 13
// baseline (142.352 us; speedup 1.0000x reference)
//
#include <hip/hip_runtime.h>
#include <hip/hip_bf16.h>
#include <hip/hip_fp8.h>
#include <cstdint>

// Varkeys: out[b,c] = sum_d values[d,c] / (||k_d||^2 - 2 k_d.x_b + ||x_b||^2 + EPS)
// R13 = R12 + phase-B values-fragments moved from LDS to registers:
// fragment-major vw2 (1KB lane-linear tiles), 8 coalesced loads at it-top
// (T14 prefetch, L2-resident), vT LDS buffer deleted, ledger 12/12/2.
// LDS = ks dbuf 32KB + kT 9KB = 41KB/WG. xq stays M=1 (32 VGPR, no spill).
// B=4096 D=16384 K=512 C=100 (padded 128).

#define BSZ   4096
#define DSZ   16384
#define KSZ   512
#define CC    100
#define CP    128
#define EPSV  1e-4f

#define BM     64
#define BD     64
#define DSPLIT 8
#define DCHUNK (DSZ / DSPLIT)   // 2048
#define NITER  (DCHUNK / BD)    // 32
#define KTS    72               // kT row stride in u16

typedef short  short8 __attribute__((ext_vector_type(8)));
typedef float  f32x4  __attribute__((ext_vector_type(4)));
typedef long   lng2   __attribute__((ext_vector_type(2)));
typedef unsigned int   u32;
typedef unsigned short u16;
typedef unsigned char  u8;

__device__ __forceinline__ u16 f2bf(float f) {
    union { float f; u32 u; } cv; cv.f = f;
    u32 u = cv.u;
    u += 0x7fffu + ((u >> 16) & 1u);   // RNE
    return (u16)(u >> 16);
}
__device__ __forceinline__ u32 pack2(float a, float b) {
    return (u32)f2bf(a) | ((u32)f2bf(b) << 16);
}
__device__ __forceinline__ u8 f2fp8(float f) {
    __hip_fp8_e4m3 t(f);                // OCP e4m3fn on gfx950
    return *reinterpret_cast<u8*>(&t);
}

__device__ __forceinline__ void gload_lds16(const void* g, void* l) {
    __builtin_amdgcn_global_load_lds(
        (const __attribute__((address_space(1))) u32*)g,
        (__attribute__((address_space(3))) u32*)l, 16, 0, 0);
}

// ---------------- fused fast-path pre-kernel ----------------
// blocks [0, XK_BLOCKS): x,keys -> fp8 paired-fragment layout + row norms.
// blocks [XK_BLOCKS, +V_BLOCKS): values -> vw2 fragment-major bf16 tiles.
#define XK_BLOCKS ((DSZ + BSZ) / 4)
#define V_BLOCKS  ((CP * DSZ / 8) / 256)

__global__ __launch_bounds__(256)
void convert_all(const float* __restrict__ x, const float* __restrict__ keys,
                 const float* __restrict__ values,
                 u8* __restrict__ xw, u8* __restrict__ kw, u8* __restrict__ vw2,
                 float* __restrict__ kk, float* __restrict__ xx)
{
    const int tid = threadIdx.x;
    if (blockIdx.x < XK_BLOCKS) {
        const int wid = tid >> 6, lane = tid & 63;
        const int row = blockIdx.x * 4 + wid;           // 0..20479
        const float* src; u8* dst; float* nrm; int r;
        if (row < DSZ) { r = row;       src = keys + (size_t)r * KSZ; dst = kw + (size_t)r * KSZ; nrm = kk + r; }
        else           { r = row - DSZ; src = x    + (size_t)r * KSZ; dst = xw + (size_t)r * KSZ; nrm = xx + r; }

        float4 v0 = *reinterpret_cast<const float4*>(src + lane * 8);
        float4 v1 = *reinterpret_cast<const float4*>(src + lane * 8 + 4);
        float s = v0.x*v0.x + v0.y*v0.y + v0.z*v0.z + v0.w*v0.w
                + v1.x*v1.x + v1.y*v1.y + v1.z*v1.z + v1.w*v1.w;

        unsigned long long pk = 0;
        pk |= (unsigned long long)f2fp8(v0.x);
        pk |= (unsigned long long)f2fp8(v0.y) << 8;
        pk |= (unsigned long long)f2fp8(v0.z) << 16;
        pk |= (unsigned long long)f2fp8(v0.w) << 24;
        pk |= (unsigned long long)f2fp8(v1.x) << 32;
        pk |= (unsigned long long)f2fp8(v1.y) << 40;
        pk |= (unsigned long long)f2fp8(v1.z) << 48;
        pk |= (unsigned long long)f2fp8(v1.w) << 56;

        const int j = lane >> 2, hi_l = lane & 3;
        const int ch = j >> 3, jl = j & 7, jj = jl >> 1, f = jl & 1;
        const int off = ch * 256 + (((jj * 64 + hi_l * 16)) ^ ((r & 7) << 4)) + f * 8;
        *reinterpret_cast<unsigned long long*>(dst + off) = pk;

        s += __shfl_xor(s, 1);  s += __shfl_xor(s, 2);  s += __shfl_xor(s, 4);
        s += __shfl_xor(s, 8);  s += __shfl_xor(s, 16); s += __shfl_xor(s, 32);
        if (lane == 0) *nrm = s;
    } else {
        // vw2: tile t = g*16 + wn*8 + nh*4 + hh*2 + kst (1KB each);
        // lane l holds V^T[c][k..k+7] bf16 at t*1024 + l*16,
        // c = wn*64+nh*32+hh*16+(l&15), k = g*64+kst*32+(l>>4)*8.
        const int gid  = (blockIdx.x - XK_BLOCKS) * 256 + tid;   // 0..262143
        const int lane = gid & 63;
        const int t    = gid >> 6;                               // 0..4095
        const int kst = t & 1, hh = (t >> 1) & 1, nh = (t >> 2) & 1, wn = (t >> 3) & 1;
        const int g   = t >> 4;                                  // 0..255
        const int c   = wn * 64 + nh * 32 + hh * 16 + (lane & 15);
        const int k0  = g * 64 + kst * 32 + (lane >> 4) * 8;
        uint4 w = make_uint4(0, 0, 0, 0);
        if (c < CC) {
            float f[8];
#pragma unroll
            for (int e = 0; e < 8; ++e) f[e] = values[(size_t)(k0 + e) * CC + c];
            w.x = pack2(f[0], f[1]); w.y = pack2(f[2], f[3]);
            w.z = pack2(f[4], f[5]); w.w = pack2(f[6], f[7]);
        }
        *reinterpret_cast<uint4*>(vw2 + (size_t)t * 1024 + lane * 16) = w;
    }
}

// ---------------- fast main kernel: fp8 phase A, vb in registers ----------------
__global__ __launch_bounds__(512, 4)
void varkeys_fast(const u8* __restrict__ xw, const u8* __restrict__ kw,
                  const u8* __restrict__ vw2, const float* __restrict__ kkp,
                  const float* __restrict__ xxp, float* __restrict__ out)
{
    __shared__ __align__(16) u8  ksb0[BD * 256];    // 16KB keys fp8 chunk buf 0
    __shared__ __align__(16) u8  ksb1[BD * 256];    // 16KB keys fp8 chunk buf 1
    __shared__ __align__(16) u16 kT[BM * KTS];      // 9KB kern tile, stride 72

    const int tid  = threadIdx.x;
    const int wid  = tid >> 6;     // 0..7
    const int lane = tid & 63;
    const int lo   = lane & 15;
    const int hi   = lane >> 4;
    const int wm   = wid >> 1;     // 0..3 : rows wm*16..+15
    const int wn   = wid & 1;      // phase A: dict half wn*32; phase B: col half wn*64

    // dchunk pinned per XCD; 64 b-blocks per dchunk.
    const int h  = blockIdx.x;
    const int by = h & 7, bx = h >> 3;
    const int bm0   = bx * BM;
    const int dbase = by * DCHUNK;

    // ---- x fragments fp8: 1 m-frag x 8 paired-slices (32 VGPR) ----
    lng2 xq[8];
    {
        const int row = bm0 + wm * 16 + lo;
        const u8* base = xw + (size_t)row * KSZ;
        const int s16 = (row & 7) << 4;
#pragma unroll
        for (int ch = 0; ch < 2; ++ch)
#pragma unroll
            for (int jj = 0; jj < 4; ++jj)
                xq[ch * 4 + jj] = *reinterpret_cast<const lng2*>(
                    base + ch * 256 + ((jj * 64 + hi * 16) ^ s16));
    }
    // ---- xx + eps in 4 registers (epilogue rows wm*16 + hi*4 + r) ----
    float xr[4];
#pragma unroll
    for (int r = 0; r < 4; ++r)
        xr[r] = xxp[bm0 + wm * 16 + hi * 4 + r] + EPSV;

    f32x4 accO[4];
#pragma unroll
    for (int n = 0; n < 4; ++n) accO[n] = f32x4{0.f, 0.f, 0.f, 0.f};

    // issue ks chunk: 16KB = 2 insts/wave. CCH = K-half, DK = dict row base.
#define IS_KS(BUFP, DK, CCH) { \
        _Pragma("unroll") \
        for (int i = 0; i < 2; ++i) { \
            const int ci = wid * 2 + i; \
            const int flat = ci * 1024 + lane * 16; \
            gload_lds16(kw + (size_t)((DK) + (flat >> 8)) * KSZ + (CCH) * 256 + (flat & 255), \
                        (char*)(BUFP) + ci * 1024); \
        } }

    // prologue: ks(it0, half0) -> ksb0
    IS_KS(ksb0, dbase, 0)

    const int swz16 = (lo & 7) << 4;   // byte XOR (fp8 ks)

    // 4 jj-steps x 4 MFMA: each b128 read = two K-32 fragments (f=0,1)
#define A16(CH, BUF)                                                                  \
    {                                                                                 \
        _Pragma("unroll")                                                             \
        for (int jj = 0; jj < 4; ++jj) {                                              \
            const int off = (jj * 64 + hi * 16) ^ swz16;                              \
            const u8* p0 = (const u8*)(BUF) + (wn * 32 + lo) * 256 + off;             \
            lng2 b0 = *reinterpret_cast<const lng2*>(p0);                             \
            lng2 b1 = *reinterpret_cast<const lng2*>(p0 + 16 * 256);                  \
            lng2 a0 = xq[(CH) * 4 + jj];                                              \
            accS[0] = __builtin_amdgcn_mfma_f32_16x16x32_fp8_fp8(a0[0], b0[0], accS[0], 0, 0, 0); \
            accS[1] = __builtin_amdgcn_mfma_f32_16x16x32_fp8_fp8(a0[0], b1[0], accS[1], 0, 0, 0); \
            accS[0] = __builtin_amdgcn_mfma_f32_16x16x32_fp8_fp8(a0[1], b0[1], accS[0], 0, 0, 0); \
            accS[1] = __builtin_amdgcn_mfma_f32_16x16x32_fp8_fp8(a0[1], b1[1], accS[1], 0, 0, 0); \
        }                                                                             \
    }

    for (int it = 0; it < NITER; ++it) {
        const int d0 = dbase + it * BD;
        const bool pf = (it < NITER - 1);

        f32x4 accS[2];
        accS[0] = f32x4{0.f, 0.f, 0.f, 0.f};
        accS[1] = f32x4{0.f, 0.f, 0.f, 0.f};

        // ---- it-top: issue ks_h1 DMA, vb register loads, kk loads ----
        // (ksb1 safe: all waves passed prev-it publish barrier after A16(1))
        IS_KS(ksb1, d0, 1)
        const u8* vbp = vw2 + (((size_t)(d0 >> 6) * 16 + wn * 8) << 10) + (size_t)lane * 16;
        short8 vb0 = *reinterpret_cast<const short8*>(vbp + 0 * 1024);
        short8 vb1 = *reinterpret_cast<const short8*>(vbp + 1 * 1024);
        short8 vb2 = *reinterpret_cast<const short8*>(vbp + 2 * 1024);
        short8 vb3 = *reinterpret_cast<const short8*>(vbp + 3 * 1024);
        short8 vb4 = *reinterpret_cast<const short8*>(vbp + 4 * 1024);
        short8 vb5 = *reinterpret_cast<const short8*>(vbp + 5 * 1024);
        short8 vb6 = *reinterpret_cast<const short8*>(vbp + 6 * 1024);
        short8 vb7 = *reinterpret_cast<const short8*>(vbp + 7 * 1024);
        const float kkf0 = kkp[d0 + wn * 32 + lo];
        const float kkf1 = kkp[d0 + wn * 32 + 16 + lo];
        asm volatile("s_waitcnt vmcnt(12)" ::: "memory");   // ks_h0 landed (12 newer ops fly)
        __builtin_amdgcn_s_barrier();
        __builtin_amdgcn_sched_barrier(0);
        A16(0, ksb0)

        __builtin_amdgcn_s_barrier();            // all waves done reading ksb0
        __builtin_amdgcn_sched_barrier(0);
        if (pf) {
            IS_KS(ksb0, d0 + BD, 0)              // prefetch next it half0
            asm volatile("s_waitcnt vmcnt(12)" ::: "memory");   // ks_h1 landed
        } else {
            asm volatile("s_waitcnt vmcnt(10)" ::: "memory");
        }
        __builtin_amdgcn_s_barrier();
        __builtin_amdgcn_sched_barrier(0);
        A16(1, ksb1)

        // ---- epilogue A: kern = rcp(kk - 2S + xx + eps) -> kT (stride 72) ----
        if (pf) { asm volatile("s_waitcnt vmcnt(2)" ::: "memory"); }   // vb+kk landed
        else    { asm volatile("s_waitcnt vmcnt(0)" ::: "memory"); }
#pragma unroll
        for (int n = 0; n < 2; ++n) {
            const int dl = wn * 32 + n * 16 + lo;
            const float kkv = n ? kkf1 : kkf0;
#pragma unroll
            for (int r = 0; r < 4; ++r) {
                const int rowl = wm * 16 + hi * 4 + r;
                const float dsq = kkv + xr[r] - 2.f * accS[n][r];
                kT[rowl * KTS + dl] = f2bf(__builtin_amdgcn_rcpf(dsq));
            }
        }
        asm volatile("s_waitcnt lgkmcnt(0)" ::: "memory");
        __builtin_amdgcn_s_barrier();            // publish kT
        __builtin_amdgcn_sched_barrier(0);

        // ---- phase B: accO += kern(64x64) . V^T, B-frags from registers ----
        {
            // kst = 0
            const int k0a = 0 * 32 + hi * 8;
            short8 a0 = *reinterpret_cast<const short8*>(&kT[(wm * 16 + lo) * KTS + k0a]);
            accO[0] = __builtin_amdgcn_mfma_f32_16x16x32_bf16(a0, vb0, accO[0], 0, 0, 0);
            accO[1] = __builtin_amdgcn_mfma_f32_16x16x32_bf16(a0, vb2, accO[1], 0, 0, 0);
            accO[2] = __builtin_amdgcn_mfma_f32_16x16x32_bf16(a0, vb4, accO[2], 0, 0, 0);
            accO[3] = __builtin_amdgcn_mfma_f32_16x16x32_bf16(a0, vb6, accO[3], 0, 0, 0);
            // kst = 1
            const int k0b = 1 * 32 + hi * 8;
            short8 a1 = *reinterpret_cast<const short8*>(&kT[(wm * 16 + lo) * KTS + k0b]);
            accO[0] = __builtin_amdgcn_mfma_f32_16x16x32_bf16(a1, vb1, accO[0], 0, 0, 0);
            accO[1] = __builtin_amdgcn_mfma_f32_16x16x32_bf16(a1, vb3, accO[1], 0, 0, 0);
            accO[2] = __builtin_amdgcn_mfma_f32_16x16x32_bf16(a1, vb5, accO[2], 0, 0, 0);
            accO[3] = __builtin_amdgcn_mfma_f32_16x16x32_bf16(a1, vb7, accO[3], 0, 0, 0);
        }
    }

    // ---- out: atomic accumulate across D-chunks ----
#pragma unroll
    for (int n = 0; n < 4; ++n) {
        const int c = wn * 64 + n * 16 + lo;
        if (c < CC) {
#pragma unroll
            for (int r = 0; r < 4; ++r) {
                const int b_ = bm0 + wm * 16 + hi * 4 + r;
                atomicAdd(&out[(size_t)b_ * CC + c], accO[n][r]);
            }
        }
    }
#undef IS_KS
#undef A16
}

// ---------------- slow fallback (round-1, passed; own FBM=128 geometry) ----------------

#define FBM 128
#define XS_STRIDE 72
#define KS_STRIDE 72
#define KT_STRIDE 72
#define VL_STRIDE 106
#define FKC 64
#define FNKC (KSZ / FKC)
#define FDSPLIT 8
#define FDCHUNK (DSZ / FDSPLIT)
#define FNITER  (FDCHUNK / BD)

__global__ __launch_bounds__(256)
void varkeys_pre(const float* __restrict__ x, const float* __restrict__ keys,
                 float* __restrict__ kk, float* __restrict__ xx)
{
    const int tid  = threadIdx.x;
    const int wid  = tid >> 6;
    const int lane = tid & 63;
    const int lo   = lane & 15;
    const int sub  = lane >> 4;
    const int row  = blockIdx.x * 16 + wid * 4 + sub;
    const float* src = (row < DSZ) ? keys + (size_t)row * KSZ
                                   : x + (size_t)(row - DSZ) * KSZ;
    float s = 0.f;
#pragma unroll
    for (int j = 0; j < 8; ++j) {
        float4 v = *reinterpret_cast<const float4*>(src + j * 64 + lo * 4);
        s += v.x * v.x + v.y * v.y + v.z * v.z + v.w * v.w;
    }
    s += __shfl_xor(s, 1); s += __shfl_xor(s, 2);
    s += __shfl_xor(s, 4); s += __shfl_xor(s, 8);
    if (lo == 0) {
        if (row < DSZ) kk[row] = s;
        else           xx[row - DSZ] = s;
    }
}

__global__ __launch_bounds__(256, 2)
void varkeys_main(const float* __restrict__ x, const float* __restrict__ keys,
                  const float* __restrict__ values, float* __restrict__ out,
                  const float* __restrict__ kk_ws, const float* __restrict__ xx_ws,
                  int use_ws)
{
    __shared__ __align__(16) u16 xs[FBM * XS_STRIDE];
    __shared__ __align__(16) u16 ks[BD * KS_STRIDE];
    __shared__ __align__(16) u16 kTf[FBM * KT_STRIDE];
    __shared__ __align__(16) u16 vls[BD * VL_STRIDE];
    __shared__ float kk_s[FDCHUNK];
    __shared__ float xx_s[FBM];

    const int tid  = threadIdx.x;
    const int wid  = tid >> 6;
    const int lane = tid & 63;
    const int lo   = lane & 15;
    const int hi   = lane >> 4;
    const int wm   = wid >> 1;
    const int wn   = wid & 1;
    const int bm0   = blockIdx.x * FBM;
    const int dbase = blockIdx.y * FDCHUNK;

    if (use_ws) {
        for (int i = tid; i < FDCHUNK; i += 256) kk_s[i] = kk_ws[dbase + i];
        if (tid < FBM) xx_s[tid] = xx_ws[bm0 + tid];
    } else {
        for (int rbase = wid * 4; rbase < FDCHUNK + FBM; rbase += 16) {
            const int row = rbase + hi;
            const float* src = (row < FDCHUNK)
                ? keys + (size_t)(dbase + row) * KSZ
                : x + (size_t)(bm0 + row - FDCHUNK) * KSZ;
            float s = 0.f;
#pragma unroll
            for (int j = 0; j < 8; ++j) {
                float4 v = *reinterpret_cast<const float4*>(src + j * 64 + lo * 4);
                s += v.x * v.x + v.y * v.y + v.z * v.z + v.w * v.w;
            }
            s += __shfl_xor(s, 1); s += __shfl_xor(s, 2);
            s += __shfl_xor(s, 4); s += __shfl_xor(s, 8);
            if (lo == 0) {
                if (row < FDCHUNK) kk_s[row] = s;
                else               xx_s[row - FDCHUNK] = s;
            }
        }
    }
    __syncthreads();

    f32x4 accO[4][4];
#pragma unroll
    for (int m = 0; m < 4; ++m)
#pragma unroll
        for (int n = 0; n < 4; ++n) accO[m][n] = f32x4{0.f, 0.f, 0.f, 0.f};

    for (int it = 0; it < FNITER; ++it) {
        const int d0 = dbase + it * BD;

        f32x4 accS[4][2];
#pragma unroll
        for (int m = 0; m < 4; ++m)
#pragma unroll
            for (int n = 0; n < 2; ++n) accS[m][n] = f32x4{0.f, 0.f, 0.f, 0.f};

        for (int kc = 0; kc < FNKC; ++kc) {
            __syncthreads();
#pragma unroll
            for (int j = 0; j < 8; ++j) {
                const int idx = tid + j * 256;
                const int row = idx >> 4, c4 = idx & 15;
                float4 v = *reinterpret_cast<const float4*>(
                    x + (size_t)(bm0 + row) * KSZ + kc * FKC + c4 * 4);
                u32* dst = reinterpret_cast<u32*>(&xs[row * XS_STRIDE + c4 * 4]);
                dst[0] = pack2(v.x, v.y); dst[1] = pack2(v.z, v.w);
            }
#pragma unroll
            for (int j = 0; j < 4; ++j) {
                const int idx = tid + j * 256;
                const int row = idx >> 4, c4 = idx & 15;
                float4 v = *reinterpret_cast<const float4*>(
                    keys + (size_t)(d0 + row) * KSZ + kc * FKC + c4 * 4);
                u32* dst = reinterpret_cast<u32*>(&ks[row * KS_STRIDE + c4 * 4]);
                dst[0] = pack2(v.x, v.y); dst[1] = pack2(v.z, v.w);
            }
            __syncthreads();
#pragma unroll
            for (int kst = 0; kst < 2; ++kst) {
                const int k0 = kst * 32 + hi * 8;
                short8 a[4], b[2];
#pragma unroll
                for (int m = 0; m < 4; ++m)
                    a[m] = *reinterpret_cast<const short8*>(
                        &xs[(wm * 64 + m * 16 + lo) * XS_STRIDE + k0]);
#pragma unroll
                for (int n = 0; n < 2; ++n)
                    b[n] = *reinterpret_cast<const short8*>(
                        &ks[(wn * 32 + n * 16 + lo) * KS_STRIDE + k0]);
#pragma unroll
                for (int m = 0; m < 4; ++m)
#pragma unroll
                    for (int n = 0; n < 2; ++n)
                        accS[m][n] = __builtin_amdgcn_mfma_f32_16x16x32_bf16(
                            a[m], b[n], accS[m][n], 0, 0, 0);
            }
        }

#pragma unroll
        for (int m = 0; m < 4; ++m)
#pragma unroll
            for (int n = 0; n < 2; ++n) {
                const int dl = wn * 32 + n * 16 + lo;
                const float kkv = kk_s[it * BD + dl];
#pragma unroll
                for (int r = 0; r < 4; ++r) {
                    const int bl = wm * 64 + m * 16 + hi * 4 + r;
                    const float dsq = kkv + xx_s[bl] - 2.f * accS[m][n][r] + EPSV;
                    kTf[bl * KT_STRIDE + dl] = f2bf(__builtin_amdgcn_rcpf(dsq));
                }
            }

#pragma unroll
        for (int j = 0; j < 7; ++j) {
            const int idx = tid + j * 256;
            if (idx < 1600) {
                const int row = idx / 25, c4 = idx % 25;
                float4 v = *reinterpret_cast<const float4*>(
                    values + (size_t)(d0 + row) * CC + c4 * 4);
                u32* dst = reinterpret_cast<u32*>(&vls[row * VL_STRIDE + c4 * 4]);
                dst[0] = pack2(v.x, v.y); dst[1] = pack2(v.z, v.w);
            }
        }
        __syncthreads();

#pragma unroll
        for (int ks2 = 0; ks2 < 2; ++ks2) {
            const int k0 = ks2 * 32 + hi * 8;
            short8 a[4], b[4];
#pragma unroll
            for (int m = 0; m < 4; ++m)
                a[m] = *reinterpret_cast<const short8*>(
                    &kTf[(wm * 64 + m * 16 + lo) * KT_STRIDE + k0]);
#pragma unroll
            for (int n = 0; n < 4; ++n) {
                const int c = wn * 64 + n * 16 + lo;
                short8 t = {0, 0, 0, 0, 0, 0, 0, 0};
                if (c < CC) {
#pragma unroll
                    for (int i = 0; i < 8; ++i)
                        t[i] = (short)vls[(k0 + i) * VL_STRIDE + c];
                }
                b[n] = t;
            }
#pragma unroll
            for (int m = 0; m < 4; ++m)
#pragma unroll
                for (int n = 0; n < 4; ++n)
                    accO[m][n] = __builtin_amdgcn_mfma_f32_16x16x32_bf16(
                        a[m], b[n], accO[m][n], 0, 0, 0);
        }
    }

#pragma unroll
    for (int m = 0; m < 4; ++m)
#pragma unroll
        for (int n = 0; n < 4; ++n) {
            const int c = wn * 64 + n * 16 + lo;
            if (c < CC) {
#pragma unroll
                for (int r = 0; r < 4; ++r) {
                    const int b_ = bm0 + wm * 64 + m * 16 + hi * 4 + r;
                    atomicAdd(&out[(size_t)b_ * CC + c], accO[m][n][r]);
                }
            }
        }
}

extern "C" void kernel_launch(void* const* d_in, const int* in_sizes, int n_in,
                              void* d_out, int out_size, void* d_ws, size_t ws_size,
                              hipStream_t stream) {
    const float* x      = (const float*)d_in[0];
    const float* keys   = (const float*)d_in[1];
    const float* values = (const float*)d_in[2];
    float* out = (float*)d_out;

    hipMemsetAsync(d_out, 0, (size_t)out_size * sizeof(float), stream);

    // fast-path ws layout (fp8 x/keys, vw2 fragment-major bf16, f32 norms)
    const size_t off_xw = 0;
    const size_t off_kw = off_xw + (size_t)BSZ * KSZ;       //  2 MB
    const size_t off_vw = off_kw + (size_t)DSZ * KSZ;       // +8 MB
    const size_t off_kk = off_vw + (size_t)CP * DSZ * 2;    // +4 MB
    const size_t off_xx = off_kk + (size_t)DSZ * 4;
    const size_t need   = off_xx + (size_t)BSZ * 4;         // ~14.1 MB

    if (ws_size >= need) {
        u8*  xw  = (u8*)((char*)d_ws + off_xw);
        u8*  kw  = (u8*)((char*)d_ws + off_kw);
        u8*  vw2 = (u8*)((char*)d_ws + off_vw);
        float* kk = (float*)((char*)d_ws + off_kk);
        float* xx = (float*)((char*)d_ws + off_xx);
        convert_all<<<dim3(XK_BLOCKS + V_BLOCKS), dim3(256), 0, stream>>>(
            x, keys, values, xw, kw, vw2, kk, xx);
        varkeys_fast<<<dim3(DSPLIT * (BSZ / BM)), dim3(512), 0, stream>>>(xw, kw, vw2, kk, xx, out);
    } else {
        const size_t ws_need = (size_t)(DSZ + BSZ) * sizeof(float);  // 80 KB
        const int use_ws = (ws_size >= ws_need) ? 1 : 0;
        float* kk = (float*)d_ws;
        float* xx = kk + DSZ;
        if (use_ws) {
            varkeys_pre<<<dim3((DSZ + BSZ) / 16), dim3(256), 0, stream>>>(x, keys, kk, xx);
        }
        varkeys_main<<<dim3(BSZ / FBM, FDSPLIT), dim3(256), 0, stream>>>(
            x, keys, values, out, kk, xx, use_ws);
    }
}

// Round 14
// 110.189 us; speedup vs baseline: 1.2919x; 1.2919x over previous
//
#include <hip/hip_runtime.h>
#include <hip/hip_bf16.h>
#include <hip/hip_fp8.h>
#include <cstdint>

// Varkeys: out[b,c] = sum_d values[d,c] / (||k_d||^2 - 2 k_d.x_b + ||x_b||^2 + EPS)
// R14 = R13 with vb (values B-fragments, 8x short8) loaded AFTER phase A
// (short live range: epilogue+phase B only) to kill R13's spills.
// Ledger (steady/last): top 4/4; mid 4/2; kk-drain 10/8; vb-drain 2/0.
// LDS = ks dbuf 32KB + kT 9KB = 41KB/WG. B=4096 D=16384 K=512 C=100 (pad 128).

#define BSZ   4096
#define DSZ   16384
#define KSZ   512
#define CC    100
#define CP    128
#define EPSV  1e-4f

#define BM     64
#define BD     64
#define DSPLIT 8
#define DCHUNK (DSZ / DSPLIT)   // 2048
#define NITER  (DCHUNK / BD)    // 32
#define KTS    72               // kT row stride in u16

typedef short  short8 __attribute__((ext_vector_type(8)));
typedef float  f32x4  __attribute__((ext_vector_type(4)));
typedef long   lng2   __attribute__((ext_vector_type(2)));
typedef unsigned int   u32;
typedef unsigned short u16;
typedef unsigned char  u8;

__device__ __forceinline__ u16 f2bf(float f) {
    union { float f; u32 u; } cv; cv.f = f;
    u32 u = cv.u;
    u += 0x7fffu + ((u >> 16) & 1u);   // RNE
    return (u16)(u >> 16);
}
__device__ __forceinline__ u32 pack2(float a, float b) {
    return (u32)f2bf(a) | ((u32)f2bf(b) << 16);
}
__device__ __forceinline__ u8 f2fp8(float f) {
    __hip_fp8_e4m3 t(f);                // OCP e4m3fn on gfx950
    return *reinterpret_cast<u8*>(&t);
}

__device__ __forceinline__ void gload_lds16(const void* g, void* l) {
    __builtin_amdgcn_global_load_lds(
        (const __attribute__((address_space(1))) u32*)g,
        (__attribute__((address_space(3))) u32*)l, 16, 0, 0);
}

// ---------------- fused fast-path pre-kernel ----------------
// blocks [0, XK_BLOCKS): x,keys -> fp8 paired-fragment layout + row norms.
// blocks [XK_BLOCKS, +V_BLOCKS): values -> vw2 fragment-major bf16 tiles.
#define XK_BLOCKS ((DSZ + BSZ) / 4)
#define V_BLOCKS  ((CP * DSZ / 8) / 256)

__global__ __launch_bounds__(256)
void convert_all(const float* __restrict__ x, const float* __restrict__ keys,
                 const float* __restrict__ values,
                 u8* __restrict__ xw, u8* __restrict__ kw, u8* __restrict__ vw2,
                 float* __restrict__ kk, float* __restrict__ xx)
{
    const int tid = threadIdx.x;
    if (blockIdx.x < XK_BLOCKS) {
        const int wid = tid >> 6, lane = tid & 63;
        const int row = blockIdx.x * 4 + wid;           // 0..20479
        const float* src; u8* dst; float* nrm; int r;
        if (row < DSZ) { r = row;       src = keys + (size_t)r * KSZ; dst = kw + (size_t)r * KSZ; nrm = kk + r; }
        else           { r = row - DSZ; src = x    + (size_t)r * KSZ; dst = xw + (size_t)r * KSZ; nrm = xx + r; }

        float4 v0 = *reinterpret_cast<const float4*>(src + lane * 8);
        float4 v1 = *reinterpret_cast<const float4*>(src + lane * 8 + 4);
        float s = v0.x*v0.x + v0.y*v0.y + v0.z*v0.z + v0.w*v0.w
                + v1.x*v1.x + v1.y*v1.y + v1.z*v1.z + v1.w*v1.w;

        unsigned long long pk = 0;
        pk |= (unsigned long long)f2fp8(v0.x);
        pk |= (unsigned long long)f2fp8(v0.y) << 8;
        pk |= (unsigned long long)f2fp8(v0.z) << 16;
        pk |= (unsigned long long)f2fp8(v0.w) << 24;
        pk |= (unsigned long long)f2fp8(v1.x) << 32;
        pk |= (unsigned long long)f2fp8(v1.y) << 40;
        pk |= (unsigned long long)f2fp8(v1.z) << 48;
        pk |= (unsigned long long)f2fp8(v1.w) << 56;

        const int j = lane >> 2, hi_l = lane & 3;
        const int ch = j >> 3, jl = j & 7, jj = jl >> 1, f = jl & 1;
        const int off = ch * 256 + (((jj * 64 + hi_l * 16)) ^ ((r & 7) << 4)) + f * 8;
        *reinterpret_cast<unsigned long long*>(dst + off) = pk;

        s += __shfl_xor(s, 1);  s += __shfl_xor(s, 2);  s += __shfl_xor(s, 4);
        s += __shfl_xor(s, 8);  s += __shfl_xor(s, 16); s += __shfl_xor(s, 32);
        if (lane == 0) *nrm = s;
    } else {
        // vw2: tile t = g*16 + wn*8 + nh*4 + hh*2 + kst (1KB each);
        // lane l holds V^T[c][k..k+7] bf16 at t*1024 + l*16,
        // c = wn*64+nh*32+hh*16+(l&15), k = g*64+kst*32+(l>>4)*8.
        const int gid  = (blockIdx.x - XK_BLOCKS) * 256 + tid;   // 0..262143
        const int lane = gid & 63;
        const int t    = gid >> 6;                               // 0..4095
        const int kst = t & 1, hh = (t >> 1) & 1, nh = (t >> 2) & 1, wn = (t >> 3) & 1;
        const int g   = t >> 4;                                  // 0..255
        const int c   = wn * 64 + nh * 32 + hh * 16 + (lane & 15);
        const int k0  = g * 64 + kst * 32 + (lane >> 4) * 8;
        uint4 w = make_uint4(0, 0, 0, 0);
        if (c < CC) {
            float f[8];
#pragma unroll
            for (int e = 0; e < 8; ++e) f[e] = values[(size_t)(k0 + e) * CC + c];
            w.x = pack2(f[0], f[1]); w.y = pack2(f[2], f[3]);
            w.z = pack2(f[4], f[5]); w.w = pack2(f[6], f[7]);
        }
        *reinterpret_cast<uint4*>(vw2 + (size_t)t * 1024 + lane * 16) = w;
    }
}

// ---------------- fast main kernel: fp8 phase A, vb short-lived registers ----------------
__global__ __launch_bounds__(512, 4)
void varkeys_fast(const u8* __restrict__ xw, const u8* __restrict__ kw,
                  const u8* __restrict__ vw2, const float* __restrict__ kkp,
                  const float* __restrict__ xxp, float* __restrict__ out)
{
    __shared__ __align__(16) u8  ksb0[BD * 256];    // 16KB keys fp8 chunk buf 0
    __shared__ __align__(16) u8  ksb1[BD * 256];    // 16KB keys fp8 chunk buf 1
    __shared__ __align__(16) u16 kT[BM * KTS];      // 9KB kern tile, stride 72

    const int tid  = threadIdx.x;
    const int wid  = tid >> 6;     // 0..7
    const int lane = tid & 63;
    const int lo   = lane & 15;
    const int hi   = lane >> 4;
    const int wm   = wid >> 1;     // 0..3 : rows wm*16..+15
    const int wn   = wid & 1;      // phase A: dict half wn*32; phase B: col half wn*64

    // dchunk pinned per XCD; 64 b-blocks per dchunk.
    const int h  = blockIdx.x;
    const int by = h & 7, bx = h >> 3;
    const int bm0   = bx * BM;
    const int dbase = by * DCHUNK;

    // ---- x fragments fp8: 1 m-frag x 8 paired-slices (32 VGPR) ----
    lng2 xq[8];
    {
        const int row = bm0 + wm * 16 + lo;
        const u8* base = xw + (size_t)row * KSZ;
        const int s16 = (row & 7) << 4;
#pragma unroll
        for (int ch = 0; ch < 2; ++ch)
#pragma unroll
            for (int jj = 0; jj < 4; ++jj)
                xq[ch * 4 + jj] = *reinterpret_cast<const lng2*>(
                    base + ch * 256 + ((jj * 64 + hi * 16) ^ s16));
    }
    // ---- xx + eps in 4 registers (epilogue rows wm*16 + hi*4 + r) ----
    float xr[4];
#pragma unroll
    for (int r = 0; r < 4; ++r)
        xr[r] = xxp[bm0 + wm * 16 + hi * 4 + r] + EPSV;

    f32x4 accO[4];
#pragma unroll
    for (int n = 0; n < 4; ++n) accO[n] = f32x4{0.f, 0.f, 0.f, 0.f};

    // issue ks chunk: 16KB = 2 insts/wave. CCH = K-half, DK = dict row base.
#define IS_KS(BUFP, DK, CCH) { \
        _Pragma("unroll") \
        for (int i = 0; i < 2; ++i) { \
            const int ci = wid * 2 + i; \
            const int flat = ci * 1024 + lane * 16; \
            gload_lds16(kw + (size_t)((DK) + (flat >> 8)) * KSZ + (CCH) * 256 + (flat & 255), \
                        (char*)(BUFP) + ci * 1024); \
        } }

    // prologue: ks(it0, half0) -> ksb0
    IS_KS(ksb0, dbase, 0)

    const int swz16 = (lo & 7) << 4;   // byte XOR (fp8 ks)

    // 4 jj-steps x 4 MFMA: each b128 read = two K-32 fragments (f=0,1)
#define A16(CH, BUF)                                                                  \
    {                                                                                 \
        _Pragma("unroll")                                                             \
        for (int jj = 0; jj < 4; ++jj) {                                              \
            const int off = (jj * 64 + hi * 16) ^ swz16;                              \
            const u8* p0 = (const u8*)(BUF) + (wn * 32 + lo) * 256 + off;             \
            lng2 b0 = *reinterpret_cast<const lng2*>(p0);                             \
            lng2 b1 = *reinterpret_cast<const lng2*>(p0 + 16 * 256);                  \
            lng2 a0 = xq[(CH) * 4 + jj];                                              \
            accS[0] = __builtin_amdgcn_mfma_f32_16x16x32_fp8_fp8(a0[0], b0[0], accS[0], 0, 0, 0); \
            accS[1] = __builtin_amdgcn_mfma_f32_16x16x32_fp8_fp8(a0[0], b1[0], accS[1], 0, 0, 0); \
            accS[0] = __builtin_amdgcn_mfma_f32_16x16x32_fp8_fp8(a0[1], b0[1], accS[0], 0, 0, 0); \
            accS[1] = __builtin_amdgcn_mfma_f32_16x16x32_fp8_fp8(a0[1], b1[1], accS[1], 0, 0, 0); \
        }                                                                             \
    }

    for (int it = 0; it < NITER; ++it) {
        const int d0 = dbase + it * BD;
        const bool pf = (it < NITER - 1);

        f32x4 accS[2];
        accS[0] = f32x4{0.f, 0.f, 0.f, 0.f};
        accS[1] = f32x4{0.f, 0.f, 0.f, 0.f};

        // ---- it-top: issue ks_h1 DMA + kk loads; drain ks_h0 ----
        IS_KS(ksb1, d0, 1)
        const float kkf0 = kkp[d0 + wn * 32 + lo];
        const float kkf1 = kkp[d0 + wn * 32 + 16 + lo];
        // queue: prev_pref(2,old) + ksb1(2) + kk(2) = 6 -> drain prev_pref
        asm volatile("s_waitcnt vmcnt(4)" ::: "memory");
        __builtin_amdgcn_s_barrier();
        __builtin_amdgcn_sched_barrier(0);
        A16(0, ksb0)

        __builtin_amdgcn_s_barrier();            // all waves done reading ksb0
        __builtin_amdgcn_sched_barrier(0);
        if (pf) {
            IS_KS(ksb0, d0 + BD, 0)              // prefetch next it half0
            // queue: ksb1(2) + kk(2) + pref(2) = 6 -> drain ksb1
            asm volatile("s_waitcnt vmcnt(4)" ::: "memory");
        } else {
            // queue: ksb1(2) + kk(2) = 4 -> drain ksb1
            asm volatile("s_waitcnt vmcnt(2)" ::: "memory");
        }
        __builtin_amdgcn_s_barrier();
        __builtin_amdgcn_sched_barrier(0);
        A16(1, ksb1)

        // ---- post-A: issue vb register loads (short live range) ----
        const u8* vbp = vw2 + (((size_t)(d0 >> 6) * 16 + wn * 8) << 10) + (size_t)lane * 16;
        short8 vb0 = *reinterpret_cast<const short8*>(vbp + 0 * 1024);
        short8 vb1 = *reinterpret_cast<const short8*>(vbp + 1 * 1024);
        short8 vb2 = *reinterpret_cast<const short8*>(vbp + 2 * 1024);
        short8 vb3 = *reinterpret_cast<const short8*>(vbp + 3 * 1024);
        short8 vb4 = *reinterpret_cast<const short8*>(vbp + 4 * 1024);
        short8 vb5 = *reinterpret_cast<const short8*>(vbp + 5 * 1024);
        short8 vb6 = *reinterpret_cast<const short8*>(vbp + 6 * 1024);
        short8 vb7 = *reinterpret_cast<const short8*>(vbp + 7 * 1024);

        // ---- epilogue A: kern = rcp(kk - 2S + xx + eps) -> kT (stride 72) ----
        // queue: kk(2) + [pref(2) if pf] + vb(8) -> drain kk
        if (pf) { asm volatile("s_waitcnt vmcnt(10)" ::: "memory"); }
        else    { asm volatile("s_waitcnt vmcnt(8)"  ::: "memory"); }
#pragma unroll
        for (int n = 0; n < 2; ++n) {
            const int dl = wn * 32 + n * 16 + lo;
            const float kkv = n ? kkf1 : kkf0;
#pragma unroll
            for (int r = 0; r < 4; ++r) {
                const int rowl = wm * 16 + hi * 4 + r;
                const float dsq = kkv + xr[r] - 2.f * accS[n][r];
                kT[rowl * KTS + dl] = f2bf(__builtin_amdgcn_rcpf(dsq));
            }
        }
        // drain vb (leave prefetch flying)
        if (pf) { asm volatile("s_waitcnt vmcnt(2)" ::: "memory"); }
        else    { asm volatile("s_waitcnt vmcnt(0)" ::: "memory"); }
        asm volatile("s_waitcnt lgkmcnt(0)" ::: "memory");
        __builtin_amdgcn_s_barrier();            // publish kT
        __builtin_amdgcn_sched_barrier(0);

        // ---- phase B: accO += kern(64x64) . V^T, B-frags from registers ----
        {
            // kst = 0
            const int k0a = 0 * 32 + hi * 8;
            short8 a0 = *reinterpret_cast<const short8*>(&kT[(wm * 16 + lo) * KTS + k0a]);
            accO[0] = __builtin_amdgcn_mfma_f32_16x16x32_bf16(a0, vb0, accO[0], 0, 0, 0);
            accO[1] = __builtin_amdgcn_mfma_f32_16x16x32_bf16(a0, vb2, accO[1], 0, 0, 0);
            accO[2] = __builtin_amdgcn_mfma_f32_16x16x32_bf16(a0, vb4, accO[2], 0, 0, 0);
            accO[3] = __builtin_amdgcn_mfma_f32_16x16x32_bf16(a0, vb6, accO[3], 0, 0, 0);
            // kst = 1
            const int k0b = 1 * 32 + hi * 8;
            short8 a1 = *reinterpret_cast<const short8*>(&kT[(wm * 16 + lo) * KTS + k0b]);
            accO[0] = __builtin_amdgcn_mfma_f32_16x16x32_bf16(a1, vb1, accO[0], 0, 0, 0);
            accO[1] = __builtin_amdgcn_mfma_f32_16x16x32_bf16(a1, vb3, accO[1], 0, 0, 0);
            accO[2] = __builtin_amdgcn_mfma_f32_16x16x32_bf16(a1, vb5, accO[2], 0, 0, 0);
            accO[3] = __builtin_amdgcn_mfma_f32_16x16x32_bf16(a1, vb7, accO[3], 0, 0, 0);
        }
    }

    // ---- out: atomic accumulate across D-chunks ----
#pragma unroll
    for (int n = 0; n < 4; ++n) {
        const int c = wn * 64 + n * 16 + lo;
        if (c < CC) {
#pragma unroll
            for (int r = 0; r < 4; ++r) {
                const int b_ = bm0 + wm * 16 + hi * 4 + r;
                atomicAdd(&out[(size_t)b_ * CC + c], accO[n][r]);
            }
        }
    }
#undef IS_KS
#undef A16
}

// ---------------- slow fallback (round-1, passed; own FBM=128 geometry) ----------------

#define FBM 128
#define XS_STRIDE 72
#define KS_STRIDE 72
#define KT_STRIDE 72
#define VL_STRIDE 106
#define FKC 64
#define FNKC (KSZ / FKC)
#define FDSPLIT 8
#define FDCHUNK (DSZ / FDSPLIT)
#define FNITER  (FDCHUNK / BD)

__global__ __launch_bounds__(256)
void varkeys_pre(const float* __restrict__ x, const float* __restrict__ keys,
                 float* __restrict__ kk, float* __restrict__ xx)
{
    const int tid  = threadIdx.x;
    const int wid  = tid >> 6;
    const int lane = tid & 63;
    const int lo   = lane & 15;
    const int sub  = lane >> 4;
    const int row  = blockIdx.x * 16 + wid * 4 + sub;
    const float* src = (row < DSZ) ? keys + (size_t)row * KSZ
                                   : x + (size_t)(row - DSZ) * KSZ;
    float s = 0.f;
#pragma unroll
    for (int j = 0; j < 8; ++j) {
        float4 v = *reinterpret_cast<const float4*>(src + j * 64 + lo * 4);
        s += v.x * v.x + v.y * v.y + v.z * v.z + v.w * v.w;
    }
    s += __shfl_xor(s, 1); s += __shfl_xor(s, 2);
    s += __shfl_xor(s, 4); s += __shfl_xor(s, 8);
    if (lo == 0) {
        if (row < DSZ) kk[row] = s;
        else           xx[row - DSZ] = s;
    }
}

__global__ __launch_bounds__(256, 2)
void varkeys_main(const float* __restrict__ x, const float* __restrict__ keys,
                  const float* __restrict__ values, float* __restrict__ out,
                  const float* __restrict__ kk_ws, const float* __restrict__ xx_ws,
                  int use_ws)
{
    __shared__ __align__(16) u16 xs[FBM * XS_STRIDE];
    __shared__ __align__(16) u16 ks[BD * KS_STRIDE];
    __shared__ __align__(16) u16 kTf[FBM * KT_STRIDE];
    __shared__ __align__(16) u16 vls[BD * VL_STRIDE];
    __shared__ float kk_s[FDCHUNK];
    __shared__ float xx_s[FBM];

    const int tid  = threadIdx.x;
    const int wid  = tid >> 6;
    const int lane = tid & 63;
    const int lo   = lane & 15;
    const int hi   = lane >> 4;
    const int wm   = wid >> 1;
    const int wn   = wid & 1;
    const int bm0   = blockIdx.x * FBM;
    const int dbase = blockIdx.y * FDCHUNK;

    if (use_ws) {
        for (int i = tid; i < FDCHUNK; i += 256) kk_s[i] = kk_ws[dbase + i];
        if (tid < FBM) xx_s[tid] = xx_ws[bm0 + tid];
    } else {
        for (int rbase = wid * 4; rbase < FDCHUNK + FBM; rbase += 16) {
            const int row = rbase + hi;
            const float* src = (row < FDCHUNK)
                ? keys + (size_t)(dbase + row) * KSZ
                : x + (size_t)(bm0 + row - FDCHUNK) * KSZ;
            float s = 0.f;
#pragma unroll
            for (int j = 0; j < 8; ++j) {
                float4 v = *reinterpret_cast<const float4*>(src + j * 64 + lo * 4);
                s += v.x * v.x + v.y * v.y + v.z * v.z + v.w * v.w;
            }
            s += __shfl_xor(s, 1); s += __shfl_xor(s, 2);
            s += __shfl_xor(s, 4); s += __shfl_xor(s, 8);
            if (lo == 0) {
                if (row < FDCHUNK) kk_s[row] = s;
                else               xx_s[row - FDCHUNK] = s;
            }
        }
    }
    __syncthreads();

    f32x4 accO[4][4];
#pragma unroll
    for (int m = 0; m < 4; ++m)
#pragma unroll
        for (int n = 0; n < 4; ++n) accO[m][n] = f32x4{0.f, 0.f, 0.f, 0.f};

    for (int it = 0; it < FNITER; ++it) {
        const int d0 = dbase + it * BD;

        f32x4 accS[4][2];
#pragma unroll
        for (int m = 0; m < 4; ++m)
#pragma unroll
            for (int n = 0; n < 2; ++n) accS[m][n] = f32x4{0.f, 0.f, 0.f, 0.f};

        for (int kc = 0; kc < FNKC; ++kc) {
            __syncthreads();
#pragma unroll
            for (int j = 0; j < 8; ++j) {
                const int idx = tid + j * 256;
                const int row = idx >> 4, c4 = idx & 15;
                float4 v = *reinterpret_cast<const float4*>(
                    x + (size_t)(bm0 + row) * KSZ + kc * FKC + c4 * 4);
                u32* dst = reinterpret_cast<u32*>(&xs[row * XS_STRIDE + c4 * 4]);
                dst[0] = pack2(v.x, v.y); dst[1] = pack2(v.z, v.w);
            }
#pragma unroll
            for (int j = 0; j < 4; ++j) {
                const int idx = tid + j * 256;
                const int row = idx >> 4, c4 = idx & 15;
                float4 v = *reinterpret_cast<const float4*>(
                    keys + (size_t)(d0 + row) * KSZ + kc * FKC + c4 * 4);
                u32* dst = reinterpret_cast<u32*>(&ks[row * KS_STRIDE + c4 * 4]);
                dst[0] = pack2(v.x, v.y); dst[1] = pack2(v.z, v.w);
            }
            __syncthreads();
#pragma unroll
            for (int kst = 0; kst < 2; ++kst) {
                const int k0 = kst * 32 + hi * 8;
                short8 a[4], b[2];
#pragma unroll
                for (int m = 0; m < 4; ++m)
                    a[m] = *reinterpret_cast<const short8*>(
                        &xs[(wm * 64 + m * 16 + lo) * XS_STRIDE + k0]);
#pragma unroll
                for (int n = 0; n < 2; ++n)
                    b[n] = *reinterpret_cast<const short8*>(
                        &ks[(wn * 32 + n * 16 + lo) * KS_STRIDE + k0]);
#pragma unroll
                for (int m = 0; m < 4; ++m)
#pragma unroll
                    for (int n = 0; n < 2; ++n)
                        accS[m][n] = __builtin_amdgcn_mfma_f32_16x16x32_bf16(
                            a[m], b[n], accS[m][n], 0, 0, 0);
            }
        }

#pragma unroll
        for (int m = 0; m < 4; ++m)
#pragma unroll
            for (int n = 0; n < 2; ++n) {
                const int dl = wn * 32 + n * 16 + lo;
                const float kkv = kk_s[it * BD + dl];
#pragma unroll
                for (int r = 0; r < 4; ++r) {
                    const int bl = wm * 64 + m * 16 + hi * 4 + r;
                    const float dsq = kkv + xx_s[bl] - 2.f * accS[m][n][r] + EPSV;
                    kTf[bl * KT_STRIDE + dl] = f2bf(__builtin_amdgcn_rcpf(dsq));
                }
            }

#pragma unroll
        for (int j = 0; j < 7; ++j) {
            const int idx = tid + j * 256;
            if (idx < 1600) {
                const int row = idx / 25, c4 = idx % 25;
                float4 v = *reinterpret_cast<const float4*>(
                    values + (size_t)(d0 + row) * CC + c4 * 4);
                u32* dst = reinterpret_cast<u32*>(&vls[row * VL_STRIDE + c4 * 4]);
                dst[0] = pack2(v.x, v.y); dst[1] = pack2(v.z, v.w);
            }
        }
        __syncthreads();

#pragma unroll
        for (int ks2 = 0; ks2 < 2; ++ks2) {
            const int k0 = ks2 * 32 + hi * 8;
            short8 a[4], b[4];
#pragma unroll
            for (int m = 0; m < 4; ++m)
                a[m] = *reinterpret_cast<const short8*>(
                    &kTf[(wm * 64 + m * 16 + lo) * KT_STRIDE + k0]);
#pragma unroll
            for (int n = 0; n < 4; ++n) {
                const int c = wn * 64 + n * 16 + lo;
                short8 t = {0, 0, 0, 0, 0, 0, 0, 0};
                if (c < CC) {
#pragma unroll
                    for (int i = 0; i < 8; ++i)
                        t[i] = (short)vls[(k0 + i) * VL_STRIDE + c];
                }
                b[n] = t;
            }
#pragma unroll
            for (int m = 0; m < 4; ++m)
#pragma unroll
                for (int n = 0; n < 4; ++n)
                    accO[m][n] = __builtin_amdgcn_mfma_f32_16x16x32_bf16(
                        a[m], b[n], accO[m][n], 0, 0, 0);
        }
    }

#pragma unroll
    for (int m = 0; m < 4; ++m)
#pragma unroll
        for (int n = 0; n < 4; ++n) {
            const int c = wn * 64 + n * 16 + lo;
            if (c < CC) {
#pragma unroll
                for (int r = 0; r < 4; ++r) {
                    const int b_ = bm0 + wm * 64 + m * 16 + hi * 4 + r;
                    atomicAdd(&out[(size_t)b_ * CC + c], accO[m][n][r]);
                }
            }
        }
}

extern "C" void kernel_launch(void* const* d_in, const int* in_sizes, int n_in,
                              void* d_out, int out_size, void* d_ws, size_t ws_size,
                              hipStream_t stream) {
    const float* x      = (const float*)d_in[0];
    const float* keys   = (const float*)d_in[1];
    const float* values = (const float*)d_in[2];
    float* out = (float*)d_out;

    hipMemsetAsync(d_out, 0, (size_t)out_size * sizeof(float), stream);

    // fast-path ws layout (fp8 x/keys, vw2 fragment-major bf16, f32 norms)
    const size_t off_xw = 0;
    const size_t off_kw = off_xw + (size_t)BSZ * KSZ;       //  2 MB
    const size_t off_vw = off_kw + (size_t)DSZ * KSZ;       // +8 MB
    const size_t off_kk = off_vw + (size_t)CP * DSZ * 2;    // +4 MB
    const size_t off_xx = off_kk + (size_t)DSZ * 4;
    const size_t need   = off_xx + (size_t)BSZ * 4;         // ~14.1 MB

    if (ws_size >= need) {
        u8*  xw  = (u8*)((char*)d_ws + off_xw);
        u8*  kw  = (u8*)((char*)d_ws + off_kw);
        u8*  vw2 = (u8*)((char*)d_ws + off_vw);
        float* kk = (float*)((char*)d_ws + off_kk);
        float* xx = (float*)((char*)d_ws + off_xx);
        convert_all<<<dim3(XK_BLOCKS + V_BLOCKS), dim3(256), 0, stream>>>(
            x, keys, values, xw, kw, vw2, kk, xx);
        varkeys_fast<<<dim3(DSPLIT * (BSZ / BM)), dim3(512), 0, stream>>>(xw, kw, vw2, kk, xx, out);
    } else {
        const size_t ws_need = (size_t)(DSZ + BSZ) * sizeof(float);  // 80 KB
        const int use_ws = (ws_size >= ws_need) ? 1 : 0;
        float* kk = (float*)d_ws;
        float* xx = kk + DSZ;
        if (use_ws) {
            varkeys_pre<<<dim3((DSZ + BSZ) / 16), dim3(256), 0, stream>>>(x, keys, kk, xx);
        }
        varkeys_main<<<dim3(BSZ / FBM, FDSPLIT), dim3(256), 0, stream>>>(
            x, keys, values, out, kk, xx, use_ws);
    }
}